// Round 8
// baseline (3487855.078 us; speedup 1.0000x reference)
//
#include <hip/hip_runtime.h>
#include <hip/hip_bf16.h>

#define B_ 128
#define T_ 200
#define H_ 512
#define G_ 2048   // 4*H
#define E_ 300

typedef unsigned short u16;
typedef unsigned int u32;

using f32x4 = __attribute__((ext_vector_type(4))) float;
using s16x8 = __attribute__((ext_vector_type(8))) short;
using u32x2 = __attribute__((ext_vector_type(2))) u32;

__device__ __forceinline__ u16 f2bf(float f) {
  u32 u = __builtin_bit_cast(u32, f);
  u32 r = (u + 0x7fffu + ((u >> 16) & 1u)) >> 16;   // RNE
  return (u16)r;
}
__device__ __forceinline__ float bf2f(u16 s) {
  return __builtin_bit_cast(float, (u32)s << 16);
}

// ---- XCD-scope (L1-bypass, L2-coherent) memory ops: sc0 only --------------
__device__ __forceinline__ s16x8 ld_h16_x(const void* p) {
  s16x8 r;
  asm volatile("global_load_dwordx4 %0, %1, off sc0" : "=v"(r) : "v"(p));
  return r;
}
__device__ __forceinline__ void st_h_x(void* p, u32 v) {   // low 16 bits
  asm volatile("global_store_short %0, %1, off sc0" :: "v"(p), "v"(v));
}
__device__ __forceinline__ u32 ld_flag_x(const void* p) {
  u32 r;
  asm volatile("global_load_dword %0, %1, off sc0\n\ts_waitcnt vmcnt(0)"
               : "=v"(r) : "v"(p) : "memory");
  return r;
}
__device__ __forceinline__ void st_flag_x(void* p, u32 v) {
  asm volatile("global_store_dword %0, %1, off sc0" :: "v"(p), "v"(v) : "memory");
}

// ---------------------------------------------------------------------------
// Wih (4H x E f32) -> bf16 padded [4H x 320]
// ---------------------------------------------------------------------------
__global__ __launch_bounds__(256) void wih_cvt(
    const float* __restrict__ W, u16* __restrict__ Wb)
{
  const int idx = blockIdx.x * 256 + threadIdx.x;   // 2048*320 total
  const int row = idx / 320, k = idx - row * 320;
  const float v = (k < E_) ? W[row * E_ + k] : 0.f;
  Wb[idx] = f2bf(v);
}

// ---------------------------------------------------------------------------
// mask bits: mb[t*4 + w] = bit i <- (tok[(w*32+i)*T + t] != 0)
// ---------------------------------------------------------------------------
__global__ __launch_bounds__(64) void mask_k(
    const int* __restrict__ tok, u32* __restrict__ mb)
{
  const int idx = blockIdx.x * 64 + threadIdx.x;
  if (idx >= T_ * 4) return;
  const int t = idx >> 2, w = idx & 3;
  u32 bits = 0;
  for (int i = 0; i < 32; ++i)
    bits |= (tok[(w * 32 + i) * T_ + t] != 0 ? 1u : 0u) << i;
  mb[idx] = bits;
}

// ---------------------------------------------------------------------------
// xg GEMM, output layout xg[m][j 512][q 4] bf16 with m = t*128 + b.
// (verified end-to-end in rounds 6/7)
// ---------------------------------------------------------------------------
__global__ __launch_bounds__(256) void xg_gemm(
    const int* __restrict__ tok, const float* __restrict__ emb,
    const u16* __restrict__ Wb, const float* __restrict__ bih,
    const float* __restrict__ bhh, u16* __restrict__ xg)
{
  __shared__ u16 Al[64 * 320];
  __shared__ u16 Bl[32 * 320];
  __shared__ int tks[64];
  const int tid = threadIdx.x;
  const int bx = blockIdx.x;
  const int m0 = bx * 64;            // m = t*128 + b ; block: t = bx>>1, b0 = (bx&1)*64
  if (tid < 64) tks[tid] = tok[((bx & 1) * 64 + tid) * T_ + (bx >> 1)];
  __syncthreads();
  {
    const int row = tid >> 2, part = tid & 3;
    const float* erow = emb + (size_t)tks[row] * E_;
    char* base = (char*)Al + row * 640;
    const int swz = (row & 7) << 4;
#pragma unroll
    for (int i = 0; i < 40; ++i) {
      const int kw = part * 40 + i;
      const int k = kw * 2;
      const float v0 = (k < E_) ? erow[k] : 0.f;
      const float v1 = (k + 1 < E_) ? erow[k + 1] : 0.f;
      *(u32*)(base + ((kw * 4) ^ swz)) = (u32)f2bf(v0) | ((u32)f2bf(v1) << 16);
    }
  }
  __syncthreads();
  const int wv = tid >> 6, ln = tid & 63, lr = ln & 15, lq = ln >> 4;
  const int arow = wv * 16 + lr;
  const char* abase = (const char*)Al + arow * 640;
  const int aswz = (arow & 7) << 4;
  const int brow = tid >> 3, bpart = tid & 7;
  char* bdst = (char*)Bl + brow * 640;
  const int bswz = (brow & 7) << 4;
  const char* b0base = (const char*)Bl + lr * 640;
  const char* b1base = (const char*)Bl + (16 + lr) * 640;
  const int bswz2 = (lr & 7) << 4;

  for (int ni = 0; ni < 8; ++ni) {
    const int n0 = blockIdx.y * 256 + ni * 32;
    {
      const u16* src = Wb + (size_t)(n0 + brow) * 320 + bpart * 40;
#pragma unroll
      for (int i = 0; i < 5; ++i) {
        s16x8 v = *(const s16x8*)(src + i * 8);
        *(s16x8*)(bdst + (((bpart * 5 + i) * 16) ^ bswz)) = v;
      }
    }
    __syncthreads();
    f32x4 acc0 = {0.f, 0.f, 0.f, 0.f}, acc1 = {0.f, 0.f, 0.f, 0.f};
#pragma unroll
    for (int ks = 0; ks < 10; ++ks) {
      const int kb = ks * 64 + lq * 16;
      s16x8 af  = *(const s16x8*)(abase  + (kb ^ aswz));
      s16x8 bf0 = *(const s16x8*)(b0base + (kb ^ bswz2));
      s16x8 bf1 = *(const s16x8*)(b1base + (kb ^ bswz2));
      acc0 = __builtin_amdgcn_mfma_f32_16x16x32_bf16(af, bf0, acc0, 0, 0, 0);
      acc1 = __builtin_amdgcn_mfma_f32_16x16x32_bf16(af, bf1, acc1, 0, 0, 0);
    }
    const int qc = n0 >> 9;            // gate quadrant (uniform per 32-tile)
    const int jA = (n0 & 511) + lr;    // j within quadrant
#pragma unroll
    for (int r = 0; r < 4; ++r) {
      const int m = m0 + wv * 16 + lq * 4 + r;
      const int gA = n0 + lr, gB = n0 + 16 + lr;
      xg[(size_t)m * 2048 + (size_t)jA * 4 + qc]        = f2bf(acc0[r] + bih[gA] + bhh[gA]);
      xg[(size_t)m * 2048 + (size_t)(jA + 16) * 4 + qc] = f2bf(acc1[r] + bih[gB] + bhh[gB]);
    }
    __syncthreads();
  }
}

// ---------------------------------------------------------------------------
// Persistent LSTM recurrence, v8: XCD-local domains, L2-scope (sc0) sync.
// 8 independent 16-batch LSTM domains, one per XCD. 512 WGs launched; each
// WG reads HW_REG_XCC_ID and atomically claims a role in its XCD's domain;
// roles >= 32 exit. Domain: 32 WGs x 512 thr; WG = j-slice (16 j). 8 waves =
// K-slices of 64 (8 MFMA/wave/step); 8-way LDS reduction; waves 0-3 run the
// epilogue (1 cell/lane: b = 4*wv+lq, j = lr). h + flags exchanged sc0-only
// (L1 bypass, XCD-L2 coherent - all members are same-XCD by construction).
// Flag discipline identical to r7: drain h stores -> barrier -> flag=t+1;
// poll (wave 0) requires all 32 flags >= t. 2 h buffers, safe as in r7.
// ---------------------------------------------------------------------------
template<int TRACK_C>
__global__ __launch_bounds__(512) void lstm_rec(
    const u16* __restrict__ xg, const float* __restrict__ Whh,
    u16* __restrict__ hbuf, const float* __restrict__ c0in,
    float* __restrict__ cOut, float* __restrict__ mhOut,
    u32* __restrict__ flags, const u32* __restrict__ maskb,
    int* __restrict__ claimed)
{
  __shared__ f32x4 red[8][4][64];   // 32 KB: [kslice][q][lane]
  __shared__ u32 info[2];
  const int tid = threadIdx.x;
  if (tid == 0) {
    u32 x;
    asm volatile("s_getreg_b32 %0, hwreg(HW_REG_XCC_ID)" : "=s"(x));
    x &= 7u;
    info[0] = x;
    info[1] = (u32)__hip_atomic_fetch_add(&claimed[x], 1, __ATOMIC_RELAXED,
                                          __HIP_MEMORY_SCOPE_AGENT);
  }
  __syncthreads();
  const int xcd = (int)info[0];
  const int role = (int)info[1];
  if (role >= 32) return;                    // surplus WG
  const int jt = role, j0 = jt * 16;
  const int bg0 = xcd * 16;                  // this domain's batch slice
  const int wv = tid >> 6, ln = tid & 63, lr = ln & 15, lq = ln >> 4;
  const int kv = wv;                         // K-slice [kv*64, +64)
  u16* hdom = hbuf + (size_t)xcd * (2 * 16 * H_);
  u32* dflags = flags + xcd * 512;           // 32 flags x 16 u32 pad

  // persistent B frags: Bf[q][ks] = Whh[q*512+j0+lr][kv*64+ks*32+lq*8 ..+8]
  s16x8 Bf[4][2];
#pragma unroll
  for (int q = 0; q < 4; ++q) {
    const float* wr = Whh + (size_t)(q * H_ + j0 + lr) * H_ + kv * 64 + lq * 8;
#pragma unroll
    for (int ks = 0; ks < 2; ++ks) {
      const float* wp = wr + ks * 32;
      s16x8 f;
#pragma unroll
      for (int i = 0; i < 8; ++i) f[i] = (short)f2bf(wp[i]);
      Bf[q][ks] = f;
    }
  }

  // epilogue state: 1 cell per lane on waves 0-3: b = 4*wv+lq, j = j0+lr
  float cst = 0.f, mbv = 0.f;
  int bglob = 0;
  if (wv < 4) {
    bglob = bg0 + wv * 4 + lq;
    if (!TRACK_C) cst = c0in[bglob * H_ + j0 + lr];
    mbv = TRACK_C ? cst : 0.f;
  }
  const u32* pp = dflags + (ln & 31) * 16;   // 32 flags, x2 lane duplication

  for (int t = 0; t < T_; ++t) {
    const u16* hrd = hdom + (t & 1) * (16 * H_);
    u16* hwr = hdom + ((t + 1) & 1) * (16 * H_);

    // epilogue waves: prefetch xg (u32x2 = 4 gates/cell) + mask bit (cached)
    u32x2 gx = {0, 0};
    u32 mk = 0;
    if (wv < 4) {
      mk = (maskb[t * 4 + (bglob >> 5)] >> (bglob & 31)) & 1u;
      gx = *(const u32x2*)(xg + (size_t)(t * 128 + bglob) * 2048
                              + (size_t)(j0 + lr) * 4);
    }

    // wave 0 polls the domain's 32 producer flags (XCD-L2 local)
    if (wv == 0 && t > 0) {
      int guard = 0;
      for (;;) {
        u32 v = ld_flag_x(pp);
        if (__all((int)(v >= (u32)t))) break;
        if (++guard > (1 << 16)) break;     // bail out instead of hanging
        __builtin_amdgcn_s_sleep(1);
      }
    }
    __syncthreads();                         // barrier A
    __builtin_amdgcn_sched_barrier(0);

    // h_t loads (sc0): A-frag row = lane&15 (16 b rows), k = kv*64+ks*32+lq*8
    s16x8 ha[2];
    const u16* hb = hrd + lr * H_ + kv * 64 + lq * 8;
    ha[0] = ld_h16_x(hb);
    ha[1] = ld_h16_x(hb + 32);
    asm volatile("s_waitcnt vmcnt(0)" ::: "memory");
    __builtin_amdgcn_sched_barrier(0);

    f32x4 acc[4];
#pragma unroll
    for (int q = 0; q < 4; ++q) acc[q] = (f32x4){0.f, 0.f, 0.f, 0.f};
#pragma unroll
    for (int ks = 0; ks < 2; ++ks)
#pragma unroll
      for (int q = 0; q < 4; ++q)
        acc[q] = __builtin_amdgcn_mfma_f32_16x16x32_bf16(ha[ks], Bf[q][ks], acc[q], 0, 0, 0);
#pragma unroll
    for (int q = 0; q < 4; ++q) red[kv][q][ln] = acc[q];
    __syncthreads();                         // barrier B

    if (wv < 4) {
      // gather full-K gates: g[q] = sum_kv red[kv][q][wv*16+lr][lq]
      const float* rp = (const float*)red;
      float g4[4];
#pragma unroll
      for (int q = 0; q < 4; ++q) {
        float s = 0.f;
#pragma unroll
        for (int k2 = 0; k2 < 8; ++k2)
          s += rp[(size_t)((k2 * 4 + q) * 64 + wv * 16 + lr) * 4 + lq];
        g4[q] = s;
      }
      const bool last = (t == T_ - 1);
      const float gi = g4[0] + bf2f((u16)gx[0]);
      const float gf = g4[1] + bf2f((u16)(gx[0] >> 16));
      const float gG = g4[2] + bf2f((u16)gx[1]);
      const float go = g4[3] + bf2f((u16)(gx[1] >> 16));
      const float si = 1.f / (1.f + __expf(-gi));
      const float sf = 1.f / (1.f + __expf(-gf));
      const float so = 1.f / (1.f + __expf(-go));
      const float tg = 2.f / (1.f + __expf(-2.f * gG)) - 1.f;
      const float cn = sf * cst + si * tg;
      const float tc = 2.f / (1.f + __expf(-2.f * cn)) - 1.f;
      const float hn = so * tc;
      cst = cn;
      if (mk) mbv = TRACK_C ? cn : hn;
      if (!last) {
        st_h_x(hwr + (wv * 4 + lq) * H_ + j0 + lr, (u32)f2bf(hn));
        asm volatile("s_waitcnt vmcnt(0)" ::: "memory");   // drain (L2 RT)
      }
    }
    __syncthreads();                         // barrier C
    if (tid == 0 && t + 1 < T_) st_flag_x(dflags + jt * 16, (u32)(t + 1));
  }

  if (wv < 4) {
    if (TRACK_C) cOut[bglob * H_ + j0 + lr] = mbv;
    else         mhOut[bglob * H_ + j0 + lr] = mbv;
  }
}

// ---------------------------------------------------------------------------
// head: logits = [mh, sim] @ fcW^T + fcb ; log_softmax
// ---------------------------------------------------------------------------
__global__ __launch_bounds__(128) void final_k(
    const float* __restrict__ mh, const float* __restrict__ sim,
    const float* __restrict__ fcW, const float* __restrict__ fcb,
    float* __restrict__ out)
{
  const int b = threadIdx.x;
  float l[3];
#pragma unroll
  for (int cc = 0; cc < 3; ++cc) {
    const float* wr = fcW + cc * (H_ + 1);
    float s = fcb[cc] + sim[b] * wr[H_];
    for (int j = 0; j < H_; ++j) s += mh[b * H_ + j] * wr[j];
    l[cc] = s;
  }
  const float m = fmaxf(l[0], fmaxf(l[1], l[2]));
  const float lse = m + logf(__expf(l[0] - m) + __expf(l[1] - m) + __expf(l[2] - m));
  out[b * 3 + 0] = l[0] - lse;
  out[b * 3 + 1] = l[1] - lse;
  out[b * 3 + 2] = l[2] - lse;
}

extern "C" void kernel_launch(void* const* d_in, const int* in_sizes, int n_in,
                              void* d_out, int out_size, void* d_ws, size_t ws_size,
                              hipStream_t stream) {
  const int*   prem = (const int*)d_in[0];
  const int*   hypo = (const int*)d_in[1];
  const float* sim  = (const float*)d_in[2];
  const float* emb  = (const float*)d_in[3];
  const float* WihP = (const float*)d_in[4];
  const float* WhhP = (const float*)d_in[5];
  const float* bihP = (const float*)d_in[6];
  const float* bhhP = (const float*)d_in[7];
  const float* WihH = (const float*)d_in[8];
  const float* WhhH = (const float*)d_in[9];
  const float* bihH = (const float*)d_in[10];
  const float* bhhH = (const float*)d_in[11];
  const float* fcW  = (const float*)d_in[12];
  const float* fcb  = (const float*)d_in[13];
  float* out = (float*)d_out;

  char* ws = (char*)d_ws;
  const size_t XG_BYTES = (size_t)B_ * T_ * G_ * 2;       // 104,857,600
  const size_t HB_OFF  = XG_BYTES;                        // 8 dom x 2 x 16 x 512 u16
  const size_t CL_OFF  = HB_OFF + (size_t)8 * 2 * 16 * H_ * 2;   // 256 KB
  const size_t MH_OFF  = CL_OFF + (size_t)B_ * H_ * 4;
  const size_t FL_OFF  = MH_OFF + (size_t)B_ * H_ * 4;    // 2 x 16 KB flags
  const size_t CLM_OFF = FL_OFF + 32768;                  // 2 x 8 ints
  const size_t MK_OFF  = CLM_OFF + 64;                    // 2 x 4 KB maskbits
  const size_t WB_OFF  = MK_OFF + 8192;
  const size_t NEED    = WB_OFF + (size_t)G_ * 320 * 2;   // ~107 MB
  if (ws_size < NEED) return;  // visible failure instead of OOB corruption

  u16*   xg    = (u16*)ws;
  u16*   hbuf  = (u16*)(ws + HB_OFF);
  float* cLast = (float*)(ws + CL_OFF);
  float* mh    = (float*)(ws + MH_OFF);
  u32*   flagsP = (u32*)(ws + FL_OFF);        // 8 dom x 32 x 64B
  u32*   flagsH = flagsP + 4096;
  int*   clmP  = (int*)(ws + CLM_OFF);
  int*   clmH  = clmP + 8;
  u32*   maskbP = (u32*)(ws + MK_OFF);        // 200 x 4 u32
  u32*   maskbH = maskbP + 1024;
  u16*   Wb    = (u16*)(ws + WB_OFF);

  hipMemsetAsync(ws + FL_OFF, 0, 32768 + 64, stream);     // flags + claim tables

  dim3 gG(400, 8);
  wih_cvt<<<2560, 256, 0, stream>>>(WihP, Wb);
  mask_k<<<13, 64, 0, stream>>>(prem, maskbP);
  xg_gemm<<<gG, 256, 0, stream>>>(prem, emb, Wb, bihP, bhhP, xg);
  hipMemsetAsync(hbuf, 0, (size_t)8 * 2 * 16 * H_ * 2, stream);   // h0 = 0
  lstm_rec<1><<<512, 512, 0, stream>>>(xg, WhhP, hbuf, nullptr, cLast, nullptr,
                                       flagsP, maskbP, clmP);
  wih_cvt<<<2560, 256, 0, stream>>>(WihH, Wb);
  mask_k<<<13, 64, 0, stream>>>(hypo, maskbH);
  xg_gemm<<<gG, 256, 0, stream>>>(hypo, emb, Wb, bihH, bhhH, xg);
  hipMemsetAsync(hbuf, 0, (size_t)8 * 2 * 16 * H_ * 2, stream);   // h0 = 0
  lstm_rec<0><<<512, 512, 0, stream>>>(xg, WhhH, hbuf, cLast, nullptr, mh,
                                       flagsH, maskbH, clmH);
  final_k<<<1, 128, 0, stream>>>(mh, sim, fcW, fcb, out);
}

// Round 9
// 4318.174 us; speedup vs baseline: 807.7152x; 807.7152x over previous
//
#include <hip/hip_runtime.h>
#include <hip/hip_bf16.h>

#define B_ 128
#define T_ 200
#define H_ 512
#define G_ 2048   // 4*H
#define E_ 300

typedef unsigned short u16;
typedef unsigned int u32;

using f32x4 = __attribute__((ext_vector_type(4))) float;
using s16x8 = __attribute__((ext_vector_type(8))) short;
using u32x2 = __attribute__((ext_vector_type(2))) u32;

__device__ __forceinline__ u16 f2bf(float f) {
  u32 u = __builtin_bit_cast(u32, f);
  u32 r = (u + 0x7fffu + ((u >> 16) & 1u)) >> 16;   // RNE
  return (u16)r;
}
__device__ __forceinline__ float bf2f(u16 s) {
  return __builtin_bit_cast(float, (u32)s << 16);
}

// ---- device-coherent (L1/L2-bypass) memory ops: sc0 sc1 (PROVEN r3-r7) ----
__device__ __forceinline__ s16x8 ld_h16_sc(const void* p) {
  s16x8 r;
  asm volatile("global_load_dwordx4 %0, %1, off sc0 sc1" : "=v"(r) : "v"(p));
  return r;
}
__device__ __forceinline__ void st_h_sc(void* p, u32 v) {   // low 16 bits
  asm volatile("global_store_short %0, %1, off sc0 sc1" :: "v"(p), "v"(v));
}
__device__ __forceinline__ u32 ld_flag_sc(const void* p) {
  u32 r;
  asm volatile("global_load_dword %0, %1, off sc0 sc1\n\ts_waitcnt vmcnt(0)"
               : "=v"(r) : "v"(p) : "memory");
  return r;
}
__device__ __forceinline__ void st_flag_sc(void* p, u32 v) {
  asm volatile("global_store_dword %0, %1, off sc0 sc1" :: "v"(p), "v"(v) : "memory");
}

// ---------------------------------------------------------------------------
// Wih (4H x E f32) -> bf16 padded [4H x 320]
// ---------------------------------------------------------------------------
__global__ __launch_bounds__(256) void wih_cvt(
    const float* __restrict__ W, u16* __restrict__ Wb)
{
  const int idx = blockIdx.x * 256 + threadIdx.x;   // 2048*320 total
  const int row = idx / 320, k = idx - row * 320;
  const float v = (k < E_) ? W[row * E_ + k] : 0.f;
  Wb[idx] = f2bf(v);
}

// ---------------------------------------------------------------------------
// mask bits: mb[t*4 + w] = bit i <- (tok[(w*32+i)*T + t] != 0)
// ---------------------------------------------------------------------------
__global__ __launch_bounds__(64) void mask_k(
    const int* __restrict__ tok, u32* __restrict__ mb)
{
  const int idx = blockIdx.x * 64 + threadIdx.x;
  if (idx >= T_ * 4) return;
  const int t = idx >> 2, w = idx & 3;
  u32 bits = 0;
  for (int i = 0; i < 32; ++i)
    bits |= (tok[(w * 32 + i) * T_ + t] != 0 ? 1u : 0u) << i;
  mb[idx] = bits;
}

// ---------------------------------------------------------------------------
// xg GEMM, output layout xg[m][j 512][q 4] bf16 with m = t*128 + b.
// (verified end-to-end in rounds 6/7)
// ---------------------------------------------------------------------------
__global__ __launch_bounds__(256) void xg_gemm(
    const int* __restrict__ tok, const float* __restrict__ emb,
    const u16* __restrict__ Wb, const float* __restrict__ bih,
    const float* __restrict__ bhh, u16* __restrict__ xg)
{
  __shared__ u16 Al[64 * 320];
  __shared__ u16 Bl[32 * 320];
  __shared__ int tks[64];
  const int tid = threadIdx.x;
  const int bx = blockIdx.x;
  const int m0 = bx * 64;            // m = t*128 + b ; block: t = bx>>1, b0 = (bx&1)*64
  if (tid < 64) tks[tid] = tok[((bx & 1) * 64 + tid) * T_ + (bx >> 1)];
  __syncthreads();
  {
    const int row = tid >> 2, part = tid & 3;
    const float* erow = emb + (size_t)tks[row] * E_;
    char* base = (char*)Al + row * 640;
    const int swz = (row & 7) << 4;
#pragma unroll
    for (int i = 0; i < 40; ++i) {
      const int kw = part * 40 + i;
      const int k = kw * 2;
      const float v0 = (k < E_) ? erow[k] : 0.f;
      const float v1 = (k + 1 < E_) ? erow[k + 1] : 0.f;
      *(u32*)(base + ((kw * 4) ^ swz)) = (u32)f2bf(v0) | ((u32)f2bf(v1) << 16);
    }
  }
  __syncthreads();
  const int wv = tid >> 6, ln = tid & 63, lr = ln & 15, lq = ln >> 4;
  const int arow = wv * 16 + lr;
  const char* abase = (const char*)Al + arow * 640;
  const int aswz = (arow & 7) << 4;
  const int brow = tid >> 3, bpart = tid & 7;
  char* bdst = (char*)Bl + brow * 640;
  const int bswz = (brow & 7) << 4;
  const char* b0base = (const char*)Bl + lr * 640;
  const char* b1base = (const char*)Bl + (16 + lr) * 640;
  const int bswz2 = (lr & 7) << 4;

  for (int ni = 0; ni < 8; ++ni) {
    const int n0 = blockIdx.y * 256 + ni * 32;
    {
      const u16* src = Wb + (size_t)(n0 + brow) * 320 + bpart * 40;
#pragma unroll
      for (int i = 0; i < 5; ++i) {
        s16x8 v = *(const s16x8*)(src + i * 8);
        *(s16x8*)(bdst + (((bpart * 5 + i) * 16) ^ bswz)) = v;
      }
    }
    __syncthreads();
    f32x4 acc0 = {0.f, 0.f, 0.f, 0.f}, acc1 = {0.f, 0.f, 0.f, 0.f};
#pragma unroll
    for (int ks = 0; ks < 10; ++ks) {
      const int kb = ks * 64 + lq * 16;
      s16x8 af  = *(const s16x8*)(abase  + (kb ^ aswz));
      s16x8 bf0 = *(const s16x8*)(b0base + (kb ^ bswz2));
      s16x8 bf1 = *(const s16x8*)(b1base + (kb ^ bswz2));
      acc0 = __builtin_amdgcn_mfma_f32_16x16x32_bf16(af, bf0, acc0, 0, 0, 0);
      acc1 = __builtin_amdgcn_mfma_f32_16x16x32_bf16(af, bf1, acc1, 0, 0, 0);
    }
    const int qc = n0 >> 9;            // gate quadrant (uniform per 32-tile)
    const int jA = (n0 & 511) + lr;    // j within quadrant
#pragma unroll
    for (int r = 0; r < 4; ++r) {
      const int m = m0 + wv * 16 + lq * 4 + r;
      const int gA = n0 + lr, gB = n0 + 16 + lr;
      xg[(size_t)m * 2048 + (size_t)jA * 4 + qc]        = f2bf(acc0[r] + bih[gA] + bhh[gA]);
      xg[(size_t)m * 2048 + (size_t)(jA + 16) * 4 + qc] = f2bf(acc1[r] + bih[gB] + bhh[gB]);
    }
    __syncthreads();
  }
}

// ---------------------------------------------------------------------------
// Persistent LSTM recurrence, v9 = r7 protocol + LDS mailbox + pair-granular
// consume. 64 WGs x 512 thr. WG = (grp 0..1, jt 0..31). 8 waves = (bt, kh).
// Step: wave0 polls 32 device flags (tight, no sleep), publishes ready-bitmap
// to LDS; each wave consumes producer PAIRS as they arrive (load 16B chunk ->
// 4 MFMA). No barrier A. Barriers B (red ready) + C (stores drained) remain;
// they alone order kh1's red writes vs kh0's reads across steps (kh1 cannot
// pass C(t) before kh0 finished reading red at t). Mailbox bm[2] parity:
// wave0 clears bm[(t+1)&1] before barrier B(t); workers only read bm[t&1]
// between C(t-1) and B(t) -> no stale-bit race. Producer tail identical to
// r7: h stores (sc0sc1) -> drain -> barrier C -> tid0 flag store.
// ---------------------------------------------------------------------------
template<int TRACK_C>
__global__ __launch_bounds__(512, 2) void lstm_rec(
    const u16* __restrict__ xg, const float* __restrict__ Whh,
    u16* __restrict__ hbuf, const float* __restrict__ c0in,
    float* __restrict__ cOut, float* __restrict__ mhOut,
    u32* __restrict__ flags, const u32* __restrict__ maskb)
{
  __shared__ f32x4 red[4][4][64];   // 16 KB partial-sum exchange
  __shared__ u32 bmS[2];            // mailbox: ready-bitmap per step parity
  const int tid = threadIdx.x;
  const int wv = tid >> 6, ln = tid & 63, lr = ln & 15, lq = ln >> 4;
  const int bt = wv >> 1, kh = wv & 1;
  const int grp = (int)blockIdx.x >> 5, jt = (int)blockIdx.x & 31;
  const int j0 = jt * 16, bg0 = grp * 64;
  u32* gflags = flags + grp * 512;          // 32 flags x 16 u32 pad
  volatile u32* vbm = bmS;

  if (tid == 0) { bmS[0] = 0xFFFFFFFFu; bmS[1] = 0u; }  // t=0: all ready

  // persistent B fragments: Bf[q][ks] = Whh[q*512+j0+lr][kh*256+ks*32+lq*8 ..+8]
  s16x8 Bf[4][8];
#pragma unroll
  for (int q = 0; q < 4; ++q) {
    const float* wr = Whh + (size_t)(q * H_ + j0 + lr) * H_ + kh * 256 + lq * 8;
#pragma unroll
    for (int ks = 0; ks < 8; ++ks) {
      const float* wp = wr + ks * 32;
      s16x8 f;
#pragma unroll
      for (int i = 0; i < 8; ++i) f[i] = (short)f2bf(wp[i]);
      Bf[q][ks] = f;
    }
  }

  float c[4], mb[4];
#pragma unroll
  for (int r = 0; r < 4; ++r) {
    const int b = bg0 + bt * 16 + lq * 4 + r;
    float cv = 0.f;
    if (!TRACK_C) cv = c0in[b * H_ + j0 + lr];
    c[r] = cv;
    mb[r] = TRACK_C ? cv : 0.f;
  }
  __syncthreads();   // bmS + any LDS init visible

  const u32* pp = gflags + (ln & 31) * 16;   // 32 flags, x2 lane duplication
  const int mword = (bg0 + bt * 16) >> 5;    // uniform per wave
  const int mshift = (bt & 1) * 16;

  for (int t = 0; t < T_; ++t) {
    const u16* hrd = hbuf + (t & 1) * (B_ * H_);
    u16* hwr = hbuf + ((t + 1) & 1) * (B_ * H_);
    const u16* hb = hrd + (size_t)(bg0 + bt * 16 + lr) * H_ + kh * 256 + lq * 8;

    // kh0: prefetch xg (u32x2 = 4 gates/cell) + mask word (cached loads)
    u32x2 gxp[4];
    u32 mku = 0;
    if (kh == 0) {
      mku = maskb[t * 4 + mword] >> mshift;
#pragma unroll
      for (int r = 0; r < 4; ++r) {
        const int b = bg0 + bt * 16 + lq * 4 + r;
        gxp[r] = *(const u32x2*)(xg + (size_t)(t * 128 + b) * 2048
                                    + (size_t)(j0 + lr) * 4);
      }
    }

    // ---- consume h_t pair-granularly ------------------------------------
    f32x4 acc[4];
#pragma unroll
    for (int q = 0; q < 4; ++q) acc[q] = (f32x4){0.f, 0.f, 0.f, 0.f};
    s16x8 ha[8];
    u32 done = 0;

    if (wv == 0 && t > 0) {
      // wave 0: poll device flags, publish bitmap, consume own chunks
      int guard = 0;
      for (;;) {
        u32 v = ld_flag_sc(pp);
        unsigned long long bl = __ballot((int)(v >= (u32)t));
        u32 bm32 = (u32)bl;                  // lanes 0..31 = flags 0..31
        if (ln == 0) vbm[t & 1] = bm32;
        u32 win = bm32 & 0xFFFFu;            // kh==0 window
        u32 newm = 0;
#pragma unroll
        for (int s = 0; s < 8; ++s)
          if ((((win >> (2 * s)) & 3u) == 3u) && !((done >> s) & 1u))
            newm |= 1u << s;
        if (newm) {
#pragma unroll
          for (int s = 0; s < 8; ++s)
            if ((newm >> s) & 1u) ha[s] = ld_h16_sc(hb + s * 32);
          asm volatile("s_waitcnt vmcnt(0)" ::: "memory");
#pragma unroll
          for (int s = 0; s < 8; ++s)
            if ((newm >> s) & 1u) {
#pragma unroll
              for (int q = 0; q < 4; ++q)
                acc[q] = __builtin_amdgcn_mfma_f32_16x16x32_bf16(
                    ha[s], Bf[q][s], acc[q], 0, 0, 0);
            }
          done |= newm;
        }
        if (done == 0xFFu && bm32 == 0xFFFFFFFFu) break;
        if (++guard > (1 << 20)) break;     // bail out instead of hanging
      }
    } else {
      // worker waves: spin on LDS bitmap, consume pairs as they arrive
      int guard = 0;
      while (done != 0xFFu) {
        u32 bm32 = vbm[t & 1];
        u32 win = (bm32 >> (kh * 16)) & 0xFFFFu;
        u32 newm = 0;
#pragma unroll
        for (int s = 0; s < 8; ++s)
          if ((((win >> (2 * s)) & 3u) == 3u) && !((done >> s) & 1u))
            newm |= 1u << s;
        if (newm) {
#pragma unroll
          for (int s = 0; s < 8; ++s)
            if ((newm >> s) & 1u) ha[s] = ld_h16_sc(hb + s * 32);
          asm volatile("s_waitcnt vmcnt(0)" ::: "memory");
#pragma unroll
          for (int s = 0; s < 8; ++s)
            if ((newm >> s) & 1u) {
#pragma unroll
              for (int q = 0; q < 4; ++q)
                acc[q] = __builtin_amdgcn_mfma_f32_16x16x32_bf16(
                    ha[s], Bf[q][s], acc[q], 0, 0, 0);
            }
          done |= newm;
        }
        if (++guard > (1 << 22)) break;     // bail out instead of hanging
      }
    }
    if (tid == 0) vbm[(t + 1) & 1] = 0;      // prep next slot (pre-B)

    if (kh == 1) {
#pragma unroll
      for (int q = 0; q < 4; ++q) red[bt][q][ln] = acc[q];
    }
    __syncthreads();                         // barrier B: red ready
    if (kh == 0) {
#pragma unroll
      for (int q = 0; q < 4; ++q) acc[q] += red[bt][q][ln];
      const bool last = (t == T_ - 1);
#pragma unroll
      for (int r = 0; r < 4; ++r) {
        const int b = bg0 + bt * 16 + lq * 4 + r;
        const u32 lo = gxp[r][0], hi = gxp[r][1];
        const float gi = acc[0][r] + bf2f((u16)lo);
        const float gf = acc[1][r] + bf2f((u16)(lo >> 16));
        const float gG = acc[2][r] + bf2f((u16)hi);
        const float go = acc[3][r] + bf2f((u16)(hi >> 16));
        const float si = 1.f / (1.f + __expf(-gi));
        const float sf = 1.f / (1.f + __expf(-gf));
        const float so = 1.f / (1.f + __expf(-go));
        const float tg = 2.f / (1.f + __expf(-2.f * gG)) - 1.f;
        const float cn = sf * c[r] + si * tg;
        const float tc = 2.f / (1.f + __expf(-2.f * cn)) - 1.f;
        const float hn = so * tc;
        c[r] = cn;
        if ((mku >> (lq * 4 + r)) & 1u) mb[r] = TRACK_C ? cn : hn;
        if (!last) st_h_sc(hwr + (size_t)b * H_ + j0 + lr, (u32)f2bf(hn));
      }
      if (t + 1 < T_) asm volatile("s_waitcnt vmcnt(0)" ::: "memory");  // drain
    }
    __syncthreads();                         // barrier C
    if (tid == 0 && t + 1 < T_) st_flag_sc(gflags + jt * 16, (u32)(t + 1));
  }

  if (kh == 0) {
#pragma unroll
    for (int r = 0; r < 4; ++r) {
      const int b = bg0 + bt * 16 + lq * 4 + r;
      if (TRACK_C) cOut[b * H_ + j0 + lr] = mb[r];
      else         mhOut[b * H_ + j0 + lr] = mb[r];
    }
  }
}

// ---------------------------------------------------------------------------
// head: logits = [mh, sim] @ fcW^T + fcb ; log_softmax
// ---------------------------------------------------------------------------
__global__ __launch_bounds__(128) void final_k(
    const float* __restrict__ mh, const float* __restrict__ sim,
    const float* __restrict__ fcW, const float* __restrict__ fcb,
    float* __restrict__ out)
{
  const int b = threadIdx.x;
  float l[3];
#pragma unroll
  for (int cc = 0; cc < 3; ++cc) {
    const float* wr = fcW + cc * (H_ + 1);
    float s = fcb[cc] + sim[b] * wr[H_];
    for (int j = 0; j < H_; ++j) s += mh[b * H_ + j] * wr[j];
    l[cc] = s;
  }
  const float m = fmaxf(l[0], fmaxf(l[1], l[2]));
  const float lse = m + logf(__expf(l[0] - m) + __expf(l[1] - m) + __expf(l[2] - m));
  out[b * 3 + 0] = l[0] - lse;
  out[b * 3 + 1] = l[1] - lse;
  out[b * 3 + 2] = l[2] - lse;
}

extern "C" void kernel_launch(void* const* d_in, const int* in_sizes, int n_in,
                              void* d_out, int out_size, void* d_ws, size_t ws_size,
                              hipStream_t stream) {
  const int*   prem = (const int*)d_in[0];
  const int*   hypo = (const int*)d_in[1];
  const float* sim  = (const float*)d_in[2];
  const float* emb  = (const float*)d_in[3];
  const float* WihP = (const float*)d_in[4];
  const float* WhhP = (const float*)d_in[5];
  const float* bihP = (const float*)d_in[6];
  const float* bhhP = (const float*)d_in[7];
  const float* WihH = (const float*)d_in[8];
  const float* WhhH = (const float*)d_in[9];
  const float* bihH = (const float*)d_in[10];
  const float* bhhH = (const float*)d_in[11];
  const float* fcW  = (const float*)d_in[12];
  const float* fcb  = (const float*)d_in[13];
  float* out = (float*)d_out;

  char* ws = (char*)d_ws;
  const size_t XG_BYTES = (size_t)B_ * T_ * G_ * 2;       // 104,857,600
  const size_t HB_OFF = XG_BYTES;                         // 2 x 128 x 512 bf16
  const size_t CL_OFF = HB_OFF + (size_t)2 * B_ * H_ * 2;
  const size_t MH_OFF = CL_OFF + (size_t)B_ * H_ * 4;
  const size_t FL_OFF = MH_OFF + (size_t)B_ * H_ * 4;     // 2 x 8 KB flags
  const size_t MK_OFF = FL_OFF + 16384;                   // 2 x 4 KB maskbits
  const size_t WB_OFF = MK_OFF + 8192;
  const size_t NEED   = WB_OFF + (size_t)G_ * 320 * 2;    // ~107 MB
  if (ws_size < NEED) return;  // visible failure instead of OOB corruption

  u16*   xg    = (u16*)ws;
  u16*   hbuf  = (u16*)(ws + HB_OFF);
  float* cLast = (float*)(ws + CL_OFF);
  float* mh    = (float*)(ws + MH_OFF);
  u32*   flagsP = (u32*)(ws + FL_OFF);        // 2 grp x 32 x 64B
  u32*   flagsH = flagsP + 2048;
  u32*   maskbP = (u32*)(ws + MK_OFF);        // 200 x 4 u32
  u32*   maskbH = maskbP + 1024;
  u16*   Wb    = (u16*)(ws + WB_OFF);

  hipMemsetAsync(ws + FL_OFF, 0, 16384, stream);          // both flag regions

  dim3 gG(400, 8);
  wih_cvt<<<2560, 256, 0, stream>>>(WihP, Wb);
  mask_k<<<13, 64, 0, stream>>>(prem, maskbP);
  xg_gemm<<<gG, 256, 0, stream>>>(prem, emb, Wb, bihP, bhhP, xg);
  hipMemsetAsync(hbuf, 0, (size_t)B_ * H_ * 2, stream);   // h0 = 0 (buffer 0)
  lstm_rec<1><<<64, 512, 0, stream>>>(xg, WhhP, hbuf, nullptr, cLast, nullptr, flagsP, maskbP);
  wih_cvt<<<2560, 256, 0, stream>>>(WihH, Wb);
  mask_k<<<13, 64, 0, stream>>>(hypo, maskbH);
  xg_gemm<<<gG, 256, 0, stream>>>(hypo, emb, Wb, bihH, bhhH, xg);
  hipMemsetAsync(hbuf, 0, (size_t)B_ * H_ * 2, stream);   // h0 = 0 (buffer 0)
  lstm_rec<0><<<64, 512, 0, stream>>>(xg, WhhH, hbuf, cLast, nullptr, mh, flagsH, maskbH);
  final_k<<<1, 128, 0, stream>>>(mh, sim, fcW, fcb, out);
}

// Round 10
// 1990.996 us; speedup vs baseline: 1751.8139x; 2.1689x over previous
//
#include <hip/hip_runtime.h>
#include <hip/hip_bf16.h>

#define B_ 128
#define T_ 200
#define H_ 512
#define G_ 2048   // 4*H
#define E_ 300

typedef unsigned short u16;
typedef unsigned int u32;

using f32x4 = __attribute__((ext_vector_type(4))) float;
using s16x8 = __attribute__((ext_vector_type(8))) short;
using u32x2 = __attribute__((ext_vector_type(2))) u32;

__device__ __forceinline__ u16 f2bf(float f) {
  u32 u = __builtin_bit_cast(u32, f);
  u32 r = (u + 0x7fffu + ((u >> 16) & 1u)) >> 16;   // RNE
  return (u16)r;
}
__device__ __forceinline__ float bf2f(u16 s) {
  return __builtin_bit_cast(float, (u32)s << 16);
}

// ---- device-coherent (L1/L2-bypass) memory ops: sc0 sc1 (PROVEN r3-r7) ----
__device__ __forceinline__ s16x8 ld_h16_sc(const void* p) {
  s16x8 r;
  asm volatile("global_load_dwordx4 %0, %1, off sc0 sc1" : "=v"(r) : "v"(p));
  return r;
}
__device__ __forceinline__ void st_h_sc(void* p, u32 v) {   // low 16 bits
  asm volatile("global_store_short %0, %1, off sc0 sc1" :: "v"(p), "v"(v));
}
__device__ __forceinline__ u32 ld_flag_sc(const void* p) {
  u32 r;
  asm volatile("global_load_dword %0, %1, off sc0 sc1\n\ts_waitcnt vmcnt(0)"
               : "=v"(r) : "v"(p) : "memory");
  return r;
}
__device__ __forceinline__ void st_flag_sc(void* p, u32 v) {
  asm volatile("global_store_dword %0, %1, off sc0 sc1" :: "v"(p), "v"(v) : "memory");
}

// ---------------------------------------------------------------------------
// Wih (4H x E f32) -> bf16 padded [4H x 320]
// ---------------------------------------------------------------------------
__global__ __launch_bounds__(256) void wih_cvt(
    const float* __restrict__ W, u16* __restrict__ Wb)
{
  const int idx = blockIdx.x * 256 + threadIdx.x;   // 2048*320 total
  const int row = idx / 320, k = idx - row * 320;
  const float v = (k < E_) ? W[row * E_ + k] : 0.f;
  Wb[idx] = f2bf(v);
}

// ---------------------------------------------------------------------------
// mask bits: mb[t*4 + w] = bit i <- (tok[(w*32+i)*T + t] != 0)
// ---------------------------------------------------------------------------
__global__ __launch_bounds__(64) void mask_k(
    const int* __restrict__ tok, u32* __restrict__ mb)
{
  const int idx = blockIdx.x * 64 + threadIdx.x;
  if (idx >= T_ * 4) return;
  const int t = idx >> 2, w = idx & 3;
  u32 bits = 0;
  for (int i = 0; i < 32; ++i)
    bits |= (tok[(w * 32 + i) * T_ + t] != 0 ? 1u : 0u) << i;
  mb[idx] = bits;
}

// ---------------------------------------------------------------------------
// xg GEMM, output layout xg[m][j 512][q 4] bf16 with m = t*128 + b.
// (verified end-to-end in rounds 6/7)
// ---------------------------------------------------------------------------
__global__ __launch_bounds__(256) void xg_gemm(
    const int* __restrict__ tok, const float* __restrict__ emb,
    const u16* __restrict__ Wb, const float* __restrict__ bih,
    const float* __restrict__ bhh, u16* __restrict__ xg)
{
  __shared__ u16 Al[64 * 320];
  __shared__ u16 Bl[32 * 320];
  __shared__ int tks[64];
  const int tid = threadIdx.x;
  const int bx = blockIdx.x;
  const int m0 = bx * 64;            // m = t*128 + b ; block: t = bx>>1, b0 = (bx&1)*64
  if (tid < 64) tks[tid] = tok[((bx & 1) * 64 + tid) * T_ + (bx >> 1)];
  __syncthreads();
  {
    const int row = tid >> 2, part = tid & 3;
    const float* erow = emb + (size_t)tks[row] * E_;
    char* base = (char*)Al + row * 640;
    const int swz = (row & 7) << 4;
#pragma unroll
    for (int i = 0; i < 40; ++i) {
      const int kw = part * 40 + i;
      const int k = kw * 2;
      const float v0 = (k < E_) ? erow[k] : 0.f;
      const float v1 = (k + 1 < E_) ? erow[k + 1] : 0.f;
      *(u32*)(base + ((kw * 4) ^ swz)) = (u32)f2bf(v0) | ((u32)f2bf(v1) << 16);
    }
  }
  __syncthreads();
  const int wv = tid >> 6, ln = tid & 63, lr = ln & 15, lq = ln >> 4;
  const int arow = wv * 16 + lr;
  const char* abase = (const char*)Al + arow * 640;
  const int aswz = (arow & 7) << 4;
  const int brow = tid >> 3, bpart = tid & 7;
  char* bdst = (char*)Bl + brow * 640;
  const int bswz = (brow & 7) << 4;
  const char* b0base = (const char*)Bl + lr * 640;
  const char* b1base = (const char*)Bl + (16 + lr) * 640;
  const int bswz2 = (lr & 7) << 4;

  for (int ni = 0; ni < 8; ++ni) {
    const int n0 = blockIdx.y * 256 + ni * 32;
    {
      const u16* src = Wb + (size_t)(n0 + brow) * 320 + bpart * 40;
#pragma unroll
      for (int i = 0; i < 5; ++i) {
        s16x8 v = *(const s16x8*)(src + i * 8);
        *(s16x8*)(bdst + (((bpart * 5 + i) * 16) ^ bswz)) = v;
      }
    }
    __syncthreads();
    f32x4 acc0 = {0.f, 0.f, 0.f, 0.f}, acc1 = {0.f, 0.f, 0.f, 0.f};
#pragma unroll
    for (int ks = 0; ks < 10; ++ks) {
      const int kb = ks * 64 + lq * 16;
      s16x8 af  = *(const s16x8*)(abase  + (kb ^ aswz));
      s16x8 bf0 = *(const s16x8*)(b0base + (kb ^ bswz2));
      s16x8 bf1 = *(const s16x8*)(b1base + (kb ^ bswz2));
      acc0 = __builtin_amdgcn_mfma_f32_16x16x32_bf16(af, bf0, acc0, 0, 0, 0);
      acc1 = __builtin_amdgcn_mfma_f32_16x16x32_bf16(af, bf1, acc1, 0, 0, 0);
    }
    const int qc = n0 >> 9;            // gate quadrant (uniform per 32-tile)
    const int jA = (n0 & 511) + lr;    // j within quadrant
#pragma unroll
    for (int r = 0; r < 4; ++r) {
      const int m = m0 + wv * 16 + lq * 4 + r;
      const int gA = n0 + lr, gB = n0 + 16 + lr;
      xg[(size_t)m * 2048 + (size_t)jA * 4 + qc]        = f2bf(acc0[r] + bih[gA] + bhh[gA]);
      xg[(size_t)m * 2048 + (size_t)(jA + 16) * 4 + qc] = f2bf(acc1[r] + bih[gB] + bhh[gB]);
    }
    __syncthreads();
  }
}

// ---------------------------------------------------------------------------
// Persistent LSTM recurrence, v10 = r7 sync protocol, re-partitioned for
// minimum per-wave serialized work and full-chip concurrency.
// 8 batch-groups of 16 x 32 j-slice WGs = 256 WGs (1/CU) x 512 thr.
// Wave wv = K-slice [wv*64, +64): 2 UC h-loads + 8 MFMA per step.
// Wave 0 = epilogue wave: 8-way LDS red gather, 4 cells/lane, h stores,
// drain, then IMMEDIATE flag store (single producer wave -> no pre-flag
// barrier). Poll: wave 0, tight loop, 32 flags (own group only).
// Barriers: A (h ready, after poll), B (red ready), C (red consumed).
// Buffer-reuse induction as r7: flags>=t+1 => all h_t reads complete.
// ---------------------------------------------------------------------------
template<int TRACK_C>
__global__ __launch_bounds__(512, 2) void lstm_rec(
    const u16* __restrict__ xg, const float* __restrict__ Whh,
    u16* __restrict__ hbuf, const float* __restrict__ c0in,
    float* __restrict__ cOut, float* __restrict__ mhOut,
    u32* __restrict__ flags, const u32* __restrict__ maskb)
{
  __shared__ f32x4 red[8][4][64];   // 32 KB: [kslice][q][lane]
  const int tid = threadIdx.x;
  const int wv = tid >> 6, ln = tid & 63, lr = ln & 15, lq = ln >> 4;
  const int grp = (int)blockIdx.x >> 5, jt = (int)blockIdx.x & 31;
  const int j0 = jt * 16, bg0 = grp * 16;
  u32* gflags = flags + grp * 512;          // 32 flags x 16 u32 pad

  // persistent B frags: Bf[q][ks] = Whh[q*512+j0+lr][wv*64+ks*32+lq*8 ..+8]
  s16x8 Bf[4][2];
#pragma unroll
  for (int q = 0; q < 4; ++q) {
    const float* wr = Whh + (size_t)(q * H_ + j0 + lr) * H_ + wv * 64 + lq * 8;
#pragma unroll
    for (int ks = 0; ks < 2; ++ks) {
      const float* wp = wr + ks * 32;
      s16x8 f;
#pragma unroll
      for (int i = 0; i < 8; ++i) f[i] = (short)f2bf(wp[i]);
      Bf[q][ks] = f;
    }
  }

  // epilogue state (wave 0): 4 cells/lane: b = bg0 + lq*4 + r, j = j0 + lr
  float c[4], mb[4];
#pragma unroll
  for (int r = 0; r < 4; ++r) {
    const int b = bg0 + lq * 4 + r;
    float cv = 0.f;
    if (!TRACK_C && wv == 0) cv = c0in[b * H_ + j0 + lr];
    c[r] = cv;
    mb[r] = TRACK_C ? cv : 0.f;
  }

  const u32* pp = gflags + (ln & 31) * 16;   // 32 flags, x2 lane duplication
  const int mword = grp >> 1, mshift = (grp & 1) * 16;

  for (int t = 0; t < T_; ++t) {
    const u16* hrd = hbuf + (t & 1) * (B_ * H_);
    u16* hwr = hbuf + ((t + 1) & 1) * (B_ * H_);

    // wave 0: prefetch xg (u32x2 = 4 gates/cell) + mask word (cached loads)
    u32x2 gxp[4];
    u32 mku = 0;
    if (wv == 0) {
      mku = maskb[t * 4 + mword] >> mshift;
#pragma unroll
      for (int r = 0; r < 4; ++r) {
        const int b = bg0 + lq * 4 + r;
        gxp[r] = *(const u32x2*)(xg + (size_t)(t * 128 + b) * 2048
                                    + (size_t)(j0 + lr) * 4);
      }
      // poll the group's 32 producer flags (tight loop)
      if (t > 0) {
        int guard = 0;
        for (;;) {
          u32 v = ld_flag_sc(pp);
          if (__all((int)(v >= (u32)t))) break;
          if (++guard > (1 << 22)) break;   // bail out instead of hanging
          __builtin_amdgcn_s_sleep(1);
        }
      }
    }
    __syncthreads();                         // barrier A: h_t ready
    __builtin_amdgcn_sched_barrier(0);

    // h_t loads (coherent): rows = bg0+lr, k = wv*64 + ks*32 + lq*8
    s16x8 ha[2];
    const u16* hb = hrd + (size_t)(bg0 + lr) * H_ + wv * 64 + lq * 8;
    ha[0] = ld_h16_sc(hb);
    ha[1] = ld_h16_sc(hb + 32);
    asm volatile("s_waitcnt vmcnt(0)" ::: "memory");
    __builtin_amdgcn_sched_barrier(0);

    f32x4 acc[4];
#pragma unroll
    for (int q = 0; q < 4; ++q) acc[q] = (f32x4){0.f, 0.f, 0.f, 0.f};
#pragma unroll
    for (int ks = 0; ks < 2; ++ks)
#pragma unroll
      for (int q = 0; q < 4; ++q)
        acc[q] = __builtin_amdgcn_mfma_f32_16x16x32_bf16(ha[ks], Bf[q][ks], acc[q], 0, 0, 0);

    if (wv > 0) {
#pragma unroll
      for (int q = 0; q < 4; ++q) red[wv][q][ln] = acc[q];
    }
    __syncthreads();                         // barrier B: red ready
    if (wv == 0) {
#pragma unroll
      for (int kv = 1; kv < 8; ++kv)
#pragma unroll
        for (int q = 0; q < 4; ++q) acc[q] += red[kv][q][ln];
      const bool last = (t == T_ - 1);
#pragma unroll
      for (int r = 0; r < 4; ++r) {
        const int b = bg0 + lq * 4 + r;
        const u32 lo = gxp[r][0], hi = gxp[r][1];
        const float gi = acc[0][r] + bf2f((u16)lo);
        const float gf = acc[1][r] + bf2f((u16)(lo >> 16));
        const float gG = acc[2][r] + bf2f((u16)hi);
        const float go = acc[3][r] + bf2f((u16)(hi >> 16));
        const float si = 1.f / (1.f + __expf(-gi));
        const float sf = 1.f / (1.f + __expf(-gf));
        const float so = 1.f / (1.f + __expf(-go));
        const float tg = 2.f / (1.f + __expf(-2.f * gG)) - 1.f;
        const float cn = sf * c[r] + si * tg;
        const float tc = 2.f / (1.f + __expf(-2.f * cn)) - 1.f;
        const float hn = so * tc;
        c[r] = cn;
        if ((mku >> (lq * 4 + r)) & 1u) mb[r] = TRACK_C ? cn : hn;
        if (!last) st_h_sc(hwr + (size_t)b * H_ + j0 + lr, (u32)f2bf(hn));
      }
      if (t + 1 < T_) {
        asm volatile("s_waitcnt vmcnt(0)" ::: "memory");   // drain h stores
        if (ln == 0) st_flag_sc(gflags + jt * 16, (u32)(t + 1));  // off-chain
      }
    }
    __syncthreads();                         // barrier C: red consumed
  }

  if (wv == 0) {
#pragma unroll
    for (int r = 0; r < 4; ++r) {
      const int b = bg0 + lq * 4 + r;
      if (TRACK_C) cOut[b * H_ + j0 + lr] = mb[r];
      else         mhOut[b * H_ + j0 + lr] = mb[r];
    }
  }
}

// ---------------------------------------------------------------------------
// head: logits = [mh, sim] @ fcW^T + fcb ; log_softmax
// ---------------------------------------------------------------------------
__global__ __launch_bounds__(128) void final_k(
    const float* __restrict__ mh, const float* __restrict__ sim,
    const float* __restrict__ fcW, const float* __restrict__ fcb,
    float* __restrict__ out)
{
  const int b = threadIdx.x;
  float l[3];
#pragma unroll
  for (int cc = 0; cc < 3; ++cc) {
    const float* wr = fcW + cc * (H_ + 1);
    float s = fcb[cc] + sim[b] * wr[H_];
    for (int j = 0; j < H_; ++j) s += mh[b * H_ + j] * wr[j];
    l[cc] = s;
  }
  const float m = fmaxf(l[0], fmaxf(l[1], l[2]));
  const float lse = m + logf(__expf(l[0] - m) + __expf(l[1] - m) + __expf(l[2] - m));
  out[b * 3 + 0] = l[0] - lse;
  out[b * 3 + 1] = l[1] - lse;
  out[b * 3 + 2] = l[2] - lse;
}

extern "C" void kernel_launch(void* const* d_in, const int* in_sizes, int n_in,
                              void* d_out, int out_size, void* d_ws, size_t ws_size,
                              hipStream_t stream) {
  const int*   prem = (const int*)d_in[0];
  const int*   hypo = (const int*)d_in[1];
  const float* sim  = (const float*)d_in[2];
  const float* emb  = (const float*)d_in[3];
  const float* WihP = (const float*)d_in[4];
  const float* WhhP = (const float*)d_in[5];
  const float* bihP = (const float*)d_in[6];
  const float* bhhP = (const float*)d_in[7];
  const float* WihH = (const float*)d_in[8];
  const float* WhhH = (const float*)d_in[9];
  const float* bihH = (const float*)d_in[10];
  const float* bhhH = (const float*)d_in[11];
  const float* fcW  = (const float*)d_in[12];
  const float* fcb  = (const float*)d_in[13];
  float* out = (float*)d_out;

  char* ws = (char*)d_ws;
  const size_t XG_BYTES = (size_t)B_ * T_ * G_ * 2;       // 104,857,600
  const size_t HB_OFF = XG_BYTES;                         // 2 x 128 x 512 bf16
  const size_t CL_OFF = HB_OFF + (size_t)2 * B_ * H_ * 2;
  const size_t MH_OFF = CL_OFF + (size_t)B_ * H_ * 4;
  const size_t FL_OFF = MH_OFF + (size_t)B_ * H_ * 4;     // 2 x 16 KB flags
  const size_t MK_OFF = FL_OFF + 32768;                   // 2 x 4 KB maskbits
  const size_t WB_OFF = MK_OFF + 8192;
  const size_t NEED   = WB_OFF + (size_t)G_ * 320 * 2;    // ~107 MB
  if (ws_size < NEED) return;  // visible failure instead of OOB corruption

  u16*   xg    = (u16*)ws;
  u16*   hbuf  = (u16*)(ws + HB_OFF);
  float* cLast = (float*)(ws + CL_OFF);
  float* mh    = (float*)(ws + MH_OFF);
  u32*   flagsP = (u32*)(ws + FL_OFF);        // 8 grp x 32 x 64B
  u32*   flagsH = flagsP + 4096;
  u32*   maskbP = (u32*)(ws + MK_OFF);        // 200 x 4 u32
  u32*   maskbH = maskbP + 1024;
  u16*   Wb    = (u16*)(ws + WB_OFF);

  hipMemsetAsync(ws + FL_OFF, 0, 32768, stream);          // both flag regions

  dim3 gG(400, 8);
  wih_cvt<<<2560, 256, 0, stream>>>(WihP, Wb);
  mask_k<<<13, 64, 0, stream>>>(prem, maskbP);
  xg_gemm<<<gG, 256, 0, stream>>>(prem, emb, Wb, bihP, bhhP, xg);
  hipMemsetAsync(hbuf, 0, (size_t)B_ * H_ * 2, stream);   // h0 = 0 (buffer 0)
  lstm_rec<1><<<256, 512, 0, stream>>>(xg, WhhP, hbuf, nullptr, cLast, nullptr, flagsP, maskbP);
  wih_cvt<<<2560, 256, 0, stream>>>(WihH, Wb);
  mask_k<<<13, 64, 0, stream>>>(hypo, maskbH);
  xg_gemm<<<gG, 256, 0, stream>>>(hypo, emb, Wb, bihH, bhhH, xg);
  hipMemsetAsync(hbuf, 0, (size_t)B_ * H_ * 2, stream);   // h0 = 0 (buffer 0)
  lstm_rec<0><<<256, 512, 0, stream>>>(xg, WhhH, hbuf, cLast, nullptr, mh, flagsH, maskbH);
  final_k<<<1, 128, 0, stream>>>(mh, sim, fcW, fcb, out);
}